// Round 3
// baseline (155.286 us; speedup 1.0000x reference)
//
#include <hip/hip_runtime.h>

namespace {

constexpr int B = 16;
constexpr int C = 1024;
constexpr int BC = B * C;                          // 16384
constexpr long long BCC = (long long)B * C * C;    // 16777216
constexpr float EPS  = 1e-12f;
constexpr float TINY = 1e-9f;

typedef float vfloat4 __attribute__((ext_vector_type(4)));   // clang-native vec

// Pre-kernel: per-(b,j) exp tables. 48K exps total instead of 50M in the
// main loop (exp(l_j - u_i) == exp(l_j) * exp(-u_i), factor depends on j only).
__global__ __launch_bounds__(256) void precompute_exps(
    const float* __restrict__ lower,
    const float* __restrict__ upper,
    float* __restrict__ El, float* __restrict__ Eu, float* __restrict__ Em)
{
    const int idx = blockIdx.x * 256 + threadIdx.x;   // < BC
    const float l = lower[idx];
    const float u = upper[idx];
    El[idx] = __expf(l);
    Eu[idx] = __expf(u);
    Em[idx] = __expf(0.5f * (l + u));
}

// One workgroup per output row (b, i). 256 threads x 4 consecutive j.
// Inner loop is transcendental-free: table muls + v_rcp_f32 for the secant
// slope. Diagonal handled by a one-lane fixup after the loop (no per-element
// cndmask chain).
__global__ __launch_bounds__(256) void bounded_softmax_kernel(
    const float* __restrict__ lower,
    const float* __restrict__ upper,
    const float* __restrict__ El,
    const float* __restrict__ Eu,
    const float* __restrict__ Em,
    float* __restrict__ out)
{
    const int row = blockIdx.x;            // row = b*C + i
    const int b   = row >> 10;             // C == 1024
    const int i   = row & (C - 1);
    const int tid = threadIdx.x;

    const float* __restrict__ lrow = lower + b * C;
    const float* __restrict__ urow = upper + b * C;
    const float* __restrict__ Elr  = El + b * C;
    const float* __restrict__ Eur  = Eu + b * C;
    const float* __restrict__ Emr  = Em + b * C;

    const float l_i = lrow[i];
    const float u_i = urow[i];
    // exp(-u_i) = 1/exp(u_i) etc. — v_rcp_f32 of the table entries.
    const float s_el = __builtin_amdgcn_rcpf(Eur[i]);   // exp(-u_i)
    const float s_eu = __builtin_amdgcn_rcpf(Elr[i]);   // exp(-l_i)
    const float s_em = __builtin_amdgcn_rcpf(Emr[i]);   // exp(-(l_i+u_i)/2)

    const float4 l4  = *reinterpret_cast<const float4*>(lrow + tid * 4);
    const float4 u4  = *reinterpret_cast<const float4*>(urow + tid * 4);
    const float4 El4 = *reinterpret_cast<const float4*>(Elr + tid * 4);
    const float4 Eu4 = *reinterpret_cast<const float4*>(Eur + tid * 4);
    const float4 Em4 = *reinterpret_cast<const float4*>(Emr + tid * 4);
    const float ljv[4] = {l4.x, l4.y, l4.z, l4.w};
    const float ujv[4] = {u4.x, u4.y, u4.z, u4.w};
    const float Elv[4] = {El4.x, El4.y, El4.z, El4.w};
    const float Euv[4] = {Eu4.x, Eu4.y, Eu4.z, Eu4.w};
    const float Emv[4] = {Em4.x, Em4.y, Em4.z, Em4.w};

    float a_u[4], a_l[4];
    // acc: S_l, S_u, sum_a_u, sum_a_l, sum_b_u, sum_b_l  (diag included, fixed up below)
    float acc[6] = {0.f, 0.f, 0.f, 0.f, 0.f, 0.f};

    #pragma unroll
    for (int k = 0; k < 4; ++k) {
        const float l_d = ljv[k] - u_i;
        const float u_d = ujv[k] - l_i;
        const float el  = Elv[k] * s_el;           // exp(l_d)
        const float eu  = Euv[k] * s_eu;           // exp(u_d)
        const float am  = Emv[k] * s_em;           // exp(0.5*(l_d+u_d))
        const float denom = u_d - l_d;
        const float r  = __builtin_amdgcn_rcpf(denom + EPS);
        float a = (eu - el) * r;
        a = (fabsf(denom) < TINY) ? eu : a;
        const float bu = fmaf(-a, l_d, el);        // exp_l - a_u*l_d
        const float t  = 0.5f * (l_d + u_d);
        const float bl = fmaf(-am, t, am);         // a_l - a_l*t

        acc[0] += el; acc[1] += eu; acc[2] += a;
        acc[3] += am; acc[4] += bu; acc[5] += bl;
        a_u[k] = a; a_l[k] = am;
    }

    // Diagonal fixup: only the owning lane (j == i) executes; recomputes the
    // bit-identical values accumulated above and subtracts them.
    #pragma unroll
    for (int k = 0; k < 4; ++k) {
        if (tid * 4 + k == i) {
            const float l_d = ljv[k] - u_i;
            const float u_d = ujv[k] - l_i;
            const float el  = Elv[k] * s_el;
            const float eu  = Euv[k] * s_eu;
            const float am  = Emv[k] * s_em;
            const float denom = u_d - l_d;
            const float r  = __builtin_amdgcn_rcpf(denom + EPS);
            float a = (eu - el) * r;
            a = (fabsf(denom) < TINY) ? eu : a;
            const float bu = fmaf(-a, l_d, el);
            const float t  = 0.5f * (l_d + u_d);
            const float bl = fmaf(-am, t, am);
            acc[0] -= el; acc[1] -= eu; acc[2] -= a;
            acc[3] -= am; acc[4] -= bu; acc[5] -= bl;
            a_u[k] = 0.0f; a_l[k] = 0.0f;
        }
    }

    // Block reduction: wave shuffle tree, then 4 wave-partials via LDS.
    __shared__ float red[4][6];
    const int lane = tid & 63;
    const int wid  = tid >> 6;
    #pragma unroll
    for (int m = 0; m < 6; ++m) {
        float v = acc[m];
        #pragma unroll
        for (int o = 32; o > 0; o >>= 1) v += __shfl_down(v, o);
        if (lane == 0) red[wid][m] = v;
    }
    __syncthreads();

    const float S_l  = red[0][0] + red[1][0] + red[2][0] + red[3][0];
    const float S_u  = red[0][1] + red[1][1] + red[2][1] + red[3][1];
    const float SA_u = red[0][2] + red[1][2] + red[2][2] + red[3][2];
    const float SA_l = red[0][3] + red[1][3] + red[2][3] + red[3][3];
    const float SB_u = red[0][4] + red[1][4] + red[2][4] + red[3][4];
    const float SB_l = red[0][5] + red[1][5] + red[2][5] + red[3][5];

    // g(S) = 1/(1+S) relaxations (once per row; full-precision divides fine)
    const float g_l = 1.0f / (1.0f + S_l);
    const float g_u = 1.0f / (1.0f + S_u);
    const float dg  = S_u - S_l;
    float m_u = (g_u - g_l) / (dg + EPS);
    m_u = (fabsf(dg) < TINY) ? (-g_u * g_u) : m_u;
    const float c_u = g_l - m_u * S_l;
    const float m_l = -g_u * g_u;
    const float c_l = g_u - m_l * S_u;

    float* __restrict__ lower_coef = out + 2 * BC + (long long)row * C;
    float* __restrict__ upper_coef = out + 2 * BC + BCC + (long long)row * C;

    vfloat4 lv, uv;
    #pragma unroll
    for (int k = 0; k < 4; ++k) {
        const bool diag = (tid * 4 + k == i);
        lv[k] = m_l * (diag ? -SA_l : a_l[k]);
        uv[k] = m_u * (diag ? -SA_u : a_u[k]);
    }
    __builtin_nontemporal_store(lv, reinterpret_cast<vfloat4*>(lower_coef + tid * 4));
    __builtin_nontemporal_store(uv, reinterpret_cast<vfloat4*>(upper_coef + tid * 4));

    if (tid == 0) {
        const float soft_lower = fminf(fmaxf(g_u, 0.0f), 1.0f);
        const float soft_upper = fminf(fmaxf(g_l, 0.0f), 1.0f);
        out[row]                          = soft_lower;
        out[BC + row]                     = soft_upper;
        out[2 * BC + 2 * BCC + row]       = fmaf(m_l, SB_l, c_l);  // final_lower_bias
        out[2 * BC + 2 * BCC + BC + row]  = fmaf(m_u, SB_u, c_u);  // final_upper_bias
    }
}

} // namespace

extern "C" void kernel_launch(void* const* d_in, const int* in_sizes, int n_in,
                              void* d_out, int out_size, void* d_ws, size_t ws_size,
                              hipStream_t stream) {
    const float* lower = (const float*)d_in[0];
    const float* upper = (const float*)d_in[1];
    float* out = (float*)d_out;
    float* El = (float*)d_ws;
    float* Eu = El + BC;
    float* Em = Eu + BC;
    precompute_exps<<<dim3(BC / 256), dim3(256), 0, stream>>>(lower, upper, El, Eu, Em);
    bounded_softmax_kernel<<<dim3(BC), dim3(256), 0, stream>>>(lower, upper, El, Eu, Em, out);
}